// Round 4
// baseline (391.667 us; speedup 1.0000x reference)
//
#include <hip/hip_runtime.h>
#include <hip/hip_cooperative_groups.h>
#include <math.h>

namespace cg = cooperative_groups;

// y[b,t,d] = Re(z[t]),  z[t] = r*z[t-1] + x[t],  r = exp(-|decay[d]|) * e^{i*freq[d]}
//
// Fused cooperative kernel, grid (C=128, B=4) = 512 blocks @ 2 blocks/CU:
//   Phase A: per-chunk carry from zero init; x read HBM->L3; double-buffered
//            register pipeline keeps 4-8 float4 loads in flight per wave.
//   grid.sync()
//   Phase B: Kogge-Stone scan over the C=128 chunk carries; block (c,b) owns
//            the 8-channel slab [8c,8c+8); LDS-resident; multiplier r^(L*2^k)
//            by repeated squaring. Writes EXCLUSIVE prefix back to agg.
//   grid.sync()
//   Phase C: start from scanned-in state, re-read chunk x (L3-hot), emit y
//            via non-temporal stores (y never re-read; keeps x in L3).
// Chain stepped once per 4 timesteps via r^1..r^4 (2 dependent FMAs / 4 t).
// Cross-block agg traffic uses agent-scope atomics (per-XCD L2 non-coherence).
//
// SAFETY: if hipLaunchCooperativeKernel returns any error (capture issues,
// occupancy validation, ...), we fall back to 3 ordinary kernel launches of
// the same phase functions -- no hang is possible in either path.

#define D_DIM 1024
#define T_LEN 8192
#define B_BATCH 4
#define C_CHUNKS 128                  // one 8-channel slab per block in phase B
#define L_CHUNK (T_LEN / C_CHUNKS)    // 64
#define G_GROUPS (L_CHUNK / 4)        // 16 groups of 4 timesteps

typedef float floatx4 __attribute__((ext_vector_type(4)));

#define XSTRIDE ((size_t)(D_DIM / 4))

struct RPow {
  float cr1[4], ci1[4];
  float cr2[4], ci2[4];
  float cr3[4], ci3[4];
  float cr4[4], ci4[4];
};

__device__ __forceinline__ void load_rpow(const float* __restrict__ decay,
                                          const float* __restrict__ freq, int d,
                                          RPow& P) {
  float4 dv = *(const float4*)(decay + d);
  float4 fv = *(const float4*)(freq + d);
  float a[4] = {dv.x, dv.y, dv.z, dv.w};
  float w[4] = {fv.x, fv.y, fv.z, fv.w};
#pragma unroll
  for (int k = 0; k < 4; ++k) {
    float ak = fabsf(a[k]);
    float e = expf(-ak);
    float rr = e * cosf(w[k]);
    float ri = e * sinf(w[k]);
    P.cr1[k] = rr;
    P.ci1[k] = ri;
    float r2r = fmaf(rr, rr, -ri * ri);
    float r2i = 2.f * rr * ri;
    P.cr2[k] = r2r;
    P.ci2[k] = r2i;
    P.cr3[k] = fmaf(r2r, rr, -r2i * ri);
    P.ci3[k] = fmaf(r2r, ri, r2i * rr);
    P.cr4[k] = fmaf(r2r, r2r, -r2i * r2i);
    P.ci4[k] = 2.f * r2r * r2i;
  }
}

// agent-scope (device-coherent) 8-byte publish/read for cross-XCD visibility
__device__ __forceinline__ void pub2(float2* p, float xr, float xi) {
  unsigned long long u = (unsigned long long)__float_as_uint(xr) |
                         ((unsigned long long)__float_as_uint(xi) << 32);
  __hip_atomic_store((unsigned long long*)p, u, __ATOMIC_RELAXED,
                     __HIP_MEMORY_SCOPE_AGENT);
}
__device__ __forceinline__ float2 rd2(const float2* p) {
  unsigned long long u = __hip_atomic_load(
      (unsigned long long*)p, __ATOMIC_RELAXED, __HIP_MEMORY_SCOPE_AGENT);
  return make_float2(__uint_as_float((unsigned)(u & 0xffffffffull)),
                     __uint_as_float((unsigned)(u >> 32)));
}

#define LOADG(xq, gi, R0, R1, R2, R3)                    \
  {                                                      \
    const float4* _p = (xq) + (size_t)(gi) * 4 * XSTRIDE;\
    R0 = _p[0];                                          \
    R1 = _p[XSTRIDE];                                    \
    R2 = _p[2 * XSTRIDE];                                \
    R3 = _p[3 * XSTRIDE];                                \
  }

#define STOREG(yp, gi, O0, O1, O2, O3)                   \
  {                                                      \
    floatx4* _q = (yp) + (size_t)(gi) * 4 * XSTRIDE;     \
    __builtin_nontemporal_store(O0, _q);                 \
    __builtin_nontemporal_store(O1, _q + XSTRIDE);       \
    __builtin_nontemporal_store(O2, _q + 2 * XSTRIDE);   \
    __builtin_nontemporal_store(O3, _q + 3 * XSTRIDE);   \
  }

__device__ __forceinline__ void step_carry(const RPow& P, const float4& v0,
                                           const float4& v1, const float4& v2,
                                           const float4& v3, float zr[4],
                                           float zi[4]) {
  const float X0[4] = {v0.x, v0.y, v0.z, v0.w};
  const float X1[4] = {v1.x, v1.y, v1.z, v1.w};
  const float X2[4] = {v2.x, v2.y, v2.z, v2.w};
  const float X3[4] = {v3.x, v3.y, v3.z, v3.w};
#pragma unroll
  for (int k = 0; k < 4; ++k) {
    float sr = fmaf(P.cr3[k], X0[k],
                    fmaf(P.cr2[k], X1[k], fmaf(P.cr1[k], X2[k], X3[k])));
    float si = fmaf(P.ci3[k], X0[k], fmaf(P.ci2[k], X1[k], P.ci1[k] * X2[k]));
    float nr = fmaf(P.cr4[k], zr[k], fmaf(-P.ci4[k], zi[k], sr));
    float ni = fmaf(P.cr4[k], zi[k], fmaf(P.ci4[k], zr[k], si));
    zr[k] = nr;
    zi[k] = ni;
  }
}

__device__ __forceinline__ void step_out(const RPow& P, const float4& v0,
                                         const float4& v1, const float4& v2,
                                         const float4& v3, float zr[4],
                                         float zi[4], floatx4& o0, floatx4& o1,
                                         floatx4& o2, floatx4& o3) {
  const float X0[4] = {v0.x, v0.y, v0.z, v0.w};
  const float X1[4] = {v1.x, v1.y, v1.z, v1.w};
  const float X2[4] = {v2.x, v2.y, v2.z, v2.w};
  const float X3[4] = {v3.x, v3.y, v3.z, v3.w};
#pragma unroll
  for (int k = 0; k < 4; ++k) {
    // off-chain real-part outputs for t, t+1, t+2
    float y0 = fmaf(P.cr1[k], zr[k], fmaf(-P.ci1[k], zi[k], X0[k]));
    float y1 = fmaf(P.cr2[k], zr[k],
                    fmaf(-P.ci2[k], zi[k], fmaf(P.cr1[k], X0[k], X1[k])));
    float y2 = fmaf(P.cr3[k], zr[k],
                    fmaf(-P.ci3[k], zi[k],
                         fmaf(P.cr2[k], X0[k], fmaf(P.cr1[k], X1[k], X2[k]))));
    // chain step: z' = r^4 * z + s
    float sr = fmaf(P.cr3[k], X0[k],
                    fmaf(P.cr2[k], X1[k], fmaf(P.cr1[k], X2[k], X3[k])));
    float si = fmaf(P.ci3[k], X0[k], fmaf(P.ci2[k], X1[k], P.ci1[k] * X2[k]));
    float nr = fmaf(P.cr4[k], zr[k], fmaf(-P.ci4[k], zi[k], sr));
    float ni = fmaf(P.cr4[k], zi[k], fmaf(P.ci4[k], zr[k], si));
    zr[k] = nr;
    zi[k] = ni;
    o0[k] = y0;
    o1[k] = y1;
    o2[k] = y2;
    o3[k] = nr;  // Re(z[t+3])
  }
}

// ---------------- Phase A: local carry, double-buffered loads ----------------
__device__ __forceinline__ void phaseA(const float* __restrict__ x,
                                       float2* __restrict__ agg, const RPow& P,
                                       int c, int b, int d) {
  const size_t xoff = ((size_t)b * T_LEN + (size_t)c * L_CHUNK) * D_DIM + d;
  const float4* xq = (const float4*)(x + xoff);

  float zr[4] = {0.f, 0.f, 0.f, 0.f}, zi[4] = {0.f, 0.f, 0.f, 0.f};
  float4 A0, A1, A2, A3, B0, B1, B2, B3;
  LOADG(xq, 0, A0, A1, A2, A3);
  LOADG(xq, 1, B0, B1, B2, B3);
#pragma unroll
  for (int g = 0; g < G_GROUPS; g += 2) {
    step_carry(P, A0, A1, A2, A3, zr, zi);
    if (g + 2 < G_GROUPS) LOADG(xq, g + 2, A0, A1, A2, A3);
    step_carry(P, B0, B1, B2, B3, zr, zi);
    if (g + 3 < G_GROUPS) LOADG(xq, g + 3, B0, B1, B2, B3);
  }

  float2* ap = agg + ((size_t)(b * C_CHUNKS + c)) * D_DIM + d;
  pub2(ap + 0, zr[0], zi[0]);
  pub2(ap + 1, zr[1], zi[1]);
  pub2(ap + 2, zr[2], zi[2]);
  pub2(ap + 3, zr[3], zi[3]);
}

// ---------------- Phase B: Kogge-Stone scan over chunk carries ---------------
__device__ __forceinline__ void phaseB(const float* __restrict__ decay,
                                       const float* __restrict__ freq,
                                       float2* __restrict__ agg, int slab,
                                       int b, int tid) {
  __shared__ float2 A[8][C_CHUNKS + 2];
  const int dbase = slab * 8;

  {
    int dd = tid & 7;
    for (int j = tid >> 3; j < C_CHUNKS; j += 32)
      A[dd][j] = rd2(agg + ((size_t)(b * C_CHUNKS + j)) * D_DIM + dbase + dd);
  }

  // M = r^L per slab channel; squared each step -> r^(L*2^k), no large-arg trig
  float Mr[8], Mi[8];
#pragma unroll
  for (int q = 0; q < 8; ++q) {
    float aq = fabsf(decay[dbase + q]);
    float wq = freq[dbase + q];
    float e = expf(-aq * (float)L_CHUNK);
    Mr[q] = e * cosf(wq * (float)L_CHUNK);
    Mi[q] = e * sinf(wq * (float)L_CHUNK);
  }
  __syncthreads();

  const int cc = tid;
  const bool own = (cc < C_CHUNKS);
  float Ir[8], Ii[8];
  if (own) {
#pragma unroll
    for (int q = 0; q < 8; ++q) {
      float2 v = A[q][cc];
      Ir[q] = v.x;
      Ii[q] = v.y;
    }
  }

#pragma unroll
  for (int k = 0; k < 7; ++k) {  // 2^7 == C_CHUNKS
    const int off = 1 << k;
    if (own && cc >= off) {
#pragma unroll
      for (int q = 0; q < 8; ++q) {
        float2 p = A[q][cc - off];
        Ir[q] = fmaf(Mr[q], p.x, fmaf(-Mi[q], p.y, Ir[q]));
        Ii[q] = fmaf(Mr[q], p.y, fmaf(Mi[q], p.x, Ii[q]));
      }
    }
    __syncthreads();
    if (own) {
#pragma unroll
      for (int q = 0; q < 8; ++q) A[q][cc] = make_float2(Ir[q], Ii[q]);
    }
    __syncthreads();
#pragma unroll
    for (int q = 0; q < 8; ++q) {
      float nr = fmaf(Mr[q], Mr[q], -Mi[q] * Mi[q]);
      Mi[q] = 2.f * Mr[q] * Mi[q];
      Mr[q] = nr;
    }
  }

  // writeback EXCLUSIVE prefix: prefix[j] = I_inc[j-1], prefix[0] = 0
  {
    int dd = tid & 7;
    for (int j = tid >> 3; j < C_CHUNKS; j += 32) {
      float pr = 0.f, pi = 0.f;
      if (j > 0) {
        float2 v = A[dd][j - 1];
        pr = v.x;
        pi = v.y;
      }
      pub2(agg + ((size_t)(b * C_CHUNKS + j)) * D_DIM + dbase + dd, pr, pi);
    }
  }
}

// ---------------- Phase C: emit y, double-buffered, NT stores ----------------
__device__ __forceinline__ void phaseC(const float* __restrict__ x,
                                       float* __restrict__ y,
                                       const float2* __restrict__ agg,
                                       const RPow& P, int c, int b, int d) {
  const size_t xoff = ((size_t)b * T_LEN + (size_t)c * L_CHUNK) * D_DIM + d;
  const float4* xq = (const float4*)(x + xoff);
  floatx4* yp = (floatx4*)(y + xoff);

  const float2* ap = agg + ((size_t)(b * C_CHUNKS + c)) * D_DIM + d;
  float2 q0 = rd2(ap + 0), q1 = rd2(ap + 1), q2 = rd2(ap + 2), q3 = rd2(ap + 3);
  float zr[4] = {q0.x, q1.x, q2.x, q3.x};
  float zi[4] = {q0.y, q1.y, q2.y, q3.y};

  float4 A0, A1, A2, A3, B0, B1, B2, B3;
  LOADG(xq, 0, A0, A1, A2, A3);
  LOADG(xq, 1, B0, B1, B2, B3);
#pragma unroll
  for (int g = 0; g < G_GROUPS; g += 2) {
    floatx4 o0, o1, o2, o3;
    step_out(P, A0, A1, A2, A3, zr, zi, o0, o1, o2, o3);
    if (g + 2 < G_GROUPS) LOADG(xq, g + 2, A0, A1, A2, A3);
    STOREG(yp, g, o0, o1, o2, o3);
    floatx4 p0, p1, p2, p3;
    step_out(P, B0, B1, B2, B3, zr, zi, p0, p1, p2, p3);
    if (g + 3 < G_GROUPS) LOADG(xq, g + 3, B0, B1, B2, B3);
    STOREG(yp, g + 1, p0, p1, p2, p3);
  }
}

// ---------------- kernels ----------------
__global__ __launch_bounds__(256, 2) void fused_kernel(
    const float* __restrict__ x, const float* __restrict__ decay,
    const float* __restrict__ freq, float2* __restrict__ agg,
    float* __restrict__ y) {
  cg::grid_group grid = cg::this_grid();
  const int c = blockIdx.x, b = blockIdx.y, tid = threadIdx.x;
  const int d = tid * 4;

  RPow P;
  load_rpow(decay, freq, d, P);

  phaseA(x, agg, P, c, b, d);
  grid.sync();
  phaseB(decay, freq, agg, c, b, tid);
  grid.sync();
  phaseC(x, y, agg, P, c, b, d);
}

// Fallback path (ordinary launches; no grid sync needed across kernels)
__global__ __launch_bounds__(256, 2) void k_carry(
    const float* __restrict__ x, const float* __restrict__ decay,
    const float* __restrict__ freq, float2* __restrict__ agg) {
  const int c = blockIdx.x, b = blockIdx.y, tid = threadIdx.x;
  const int d = tid * 4;
  RPow P;
  load_rpow(decay, freq, d, P);
  phaseA(x, agg, P, c, b, d);
}

__global__ __launch_bounds__(256) void k_scan(
    const float* __restrict__ decay, const float* __restrict__ freq,
    float2* __restrict__ agg) {
  phaseB(decay, freq, agg, blockIdx.x, blockIdx.y, threadIdx.x);
}

__global__ __launch_bounds__(256, 2) void k_final(
    const float* __restrict__ x, const float* __restrict__ decay,
    const float* __restrict__ freq, const float2* __restrict__ agg,
    float* __restrict__ y) {
  const int c = blockIdx.x, b = blockIdx.y, tid = threadIdx.x;
  const int d = tid * 4;
  RPow P;
  load_rpow(decay, freq, d, P);
  phaseC(x, y, agg, P, c, b, d);
}

extern "C" void kernel_launch(void* const* d_in, const int* in_sizes, int n_in,
                              void* d_out, int out_size, void* d_ws, size_t ws_size,
                              hipStream_t stream) {
  const float* x     = (const float*)d_in[0];
  const float* decay = (const float*)d_in[1];
  const float* freq  = (const float*)d_in[2];
  float* y = (float*)d_out;

  float2* agg = (float2*)d_ws;  // B*C*D*8 B = 4 MiB

  dim3 grid(C_CHUNKS, B_BATCH), block(256);
  void* args[] = {(void*)&x, (void*)&decay, (void*)&freq, (void*)&agg,
                  (void*)&y};
  hipError_t err = hipLaunchCooperativeKernel((const void*)fused_kernel, grid,
                                              block, args, 0, stream);
  if (err != hipSuccess) {
    // graceful fallback: identical math, three ordinary launches
    k_carry<<<grid, block, 0, stream>>>(x, decay, freq, agg);
    k_scan<<<grid, block, 0, stream>>>(decay, freq, agg);
    k_final<<<grid, block, 0, stream>>>(x, decay, freq, agg, y);
  }
}

// Round 5
// 278.035 us; speedup vs baseline: 1.4087x; 1.4087x over previous
//
#include <hip/hip_runtime.h>
#include <math.h>

// y[b,t,d] = Re(z[t]),  z[t] = r*z[t-1] + x[t],  r = exp(-|decay[d]|) * e^{i*freq[d]}
//
// 3 ordinary kernels (graph-captured; kernel-boundary coherence -> no atomics):
//   carry : per-chunk carry from zero init. Double-buffered register pipeline
//           (2 groups of 4 timesteps in flight = 8 float4 loads/wave).
//           Chain stepped once per 4 t via r^1..r^4 (2 dependent FMAs / 4 t).
//   scan  : parallel Kogge-Stone over the C=128 chunk carries, per 8-channel
//           slab per block; LDS-resident; r^(L*2^k) by repeated squaring.
//           Writes EXCLUSIVE prefix (state entering each chunk) in place.
//   final : from scanned-in state, re-read chunk x (L3-hot after carry pass),
//           emit y via non-temporal stores (y never re-read; keeps x in L3).
//
// Round-4 lesson: fused cooperative version = 224 us dispatch + 167 us
// non-captured launch overhead; grid.sync stalls dominate (VALUBusy 3.9%).
// Traffic counters proved the memory plan minimal (FETCH 134 MiB, WRITE 148
// MiB), so this round keeps the plan and removes the barrier/atomic overhead.

#define D_DIM 1024
#define T_LEN 8192
#define B_BATCH 4
#define C_CHUNKS 128                  // 8-channel slab per block in scan
#define L_CHUNK (T_LEN / C_CHUNKS)    // 64
#define G_GROUPS (L_CHUNK / 4)        // 16 groups of 4 timesteps

typedef float floatx4 __attribute__((ext_vector_type(4)));

#define XSTRIDE ((size_t)(D_DIM / 4))

struct RPow {
  float cr1[4], ci1[4];
  float cr2[4], ci2[4];
  float cr3[4], ci3[4];
  float cr4[4], ci4[4];
};

__device__ __forceinline__ void load_rpow(const float* __restrict__ decay,
                                          const float* __restrict__ freq, int d,
                                          RPow& P) {
  float4 dv = *(const float4*)(decay + d);
  float4 fv = *(const float4*)(freq + d);
  float a[4] = {dv.x, dv.y, dv.z, dv.w};
  float w[4] = {fv.x, fv.y, fv.z, fv.w};
#pragma unroll
  for (int k = 0; k < 4; ++k) {
    float ak = fabsf(a[k]);
    float e = expf(-ak);
    float rr = e * cosf(w[k]);
    float ri = e * sinf(w[k]);
    P.cr1[k] = rr;
    P.ci1[k] = ri;
    float r2r = fmaf(rr, rr, -ri * ri);
    float r2i = 2.f * rr * ri;
    P.cr2[k] = r2r;
    P.ci2[k] = r2i;
    P.cr3[k] = fmaf(r2r, rr, -r2i * ri);
    P.ci3[k] = fmaf(r2r, ri, r2i * rr);
    P.cr4[k] = fmaf(r2r, r2r, -r2i * r2i);
    P.ci4[k] = 2.f * r2r * r2i;
  }
}

#define LOADG(xq, gi, R0, R1, R2, R3)                    \
  {                                                      \
    const float4* _p = (xq) + (size_t)(gi) * 4 * XSTRIDE;\
    R0 = _p[0];                                          \
    R1 = _p[XSTRIDE];                                    \
    R2 = _p[2 * XSTRIDE];                                \
    R3 = _p[3 * XSTRIDE];                                \
  }

#define STOREG(yp, gi, O0, O1, O2, O3)                   \
  {                                                      \
    floatx4* _q = (yp) + (size_t)(gi) * 4 * XSTRIDE;     \
    __builtin_nontemporal_store(O0, _q);                 \
    __builtin_nontemporal_store(O1, _q + XSTRIDE);       \
    __builtin_nontemporal_store(O2, _q + 2 * XSTRIDE);   \
    __builtin_nontemporal_store(O3, _q + 3 * XSTRIDE);   \
  }

__device__ __forceinline__ void step_carry(const RPow& P, const float4& v0,
                                           const float4& v1, const float4& v2,
                                           const float4& v3, float zr[4],
                                           float zi[4]) {
  const float X0[4] = {v0.x, v0.y, v0.z, v0.w};
  const float X1[4] = {v1.x, v1.y, v1.z, v1.w};
  const float X2[4] = {v2.x, v2.y, v2.z, v2.w};
  const float X3[4] = {v3.x, v3.y, v3.z, v3.w};
#pragma unroll
  for (int k = 0; k < 4; ++k) {
    float sr = fmaf(P.cr3[k], X0[k],
                    fmaf(P.cr2[k], X1[k], fmaf(P.cr1[k], X2[k], X3[k])));
    float si = fmaf(P.ci3[k], X0[k], fmaf(P.ci2[k], X1[k], P.ci1[k] * X2[k]));
    float nr = fmaf(P.cr4[k], zr[k], fmaf(-P.ci4[k], zi[k], sr));
    float ni = fmaf(P.cr4[k], zi[k], fmaf(P.ci4[k], zr[k], si));
    zr[k] = nr;
    zi[k] = ni;
  }
}

__device__ __forceinline__ void step_out(const RPow& P, const float4& v0,
                                         const float4& v1, const float4& v2,
                                         const float4& v3, float zr[4],
                                         float zi[4], floatx4& o0, floatx4& o1,
                                         floatx4& o2, floatx4& o3) {
  const float X0[4] = {v0.x, v0.y, v0.z, v0.w};
  const float X1[4] = {v1.x, v1.y, v1.z, v1.w};
  const float X2[4] = {v2.x, v2.y, v2.z, v2.w};
  const float X3[4] = {v3.x, v3.y, v3.z, v3.w};
#pragma unroll
  for (int k = 0; k < 4; ++k) {
    // off-chain real-part outputs for t, t+1, t+2
    float y0 = fmaf(P.cr1[k], zr[k], fmaf(-P.ci1[k], zi[k], X0[k]));
    float y1 = fmaf(P.cr2[k], zr[k],
                    fmaf(-P.ci2[k], zi[k], fmaf(P.cr1[k], X0[k], X1[k])));
    float y2 = fmaf(P.cr3[k], zr[k],
                    fmaf(-P.ci3[k], zi[k],
                         fmaf(P.cr2[k], X0[k], fmaf(P.cr1[k], X1[k], X2[k]))));
    // chain step: z' = r^4 * z + s
    float sr = fmaf(P.cr3[k], X0[k],
                    fmaf(P.cr2[k], X1[k], fmaf(P.cr1[k], X2[k], X3[k])));
    float si = fmaf(P.ci3[k], X0[k], fmaf(P.ci2[k], X1[k], P.ci1[k] * X2[k]));
    float nr = fmaf(P.cr4[k], zr[k], fmaf(-P.ci4[k], zi[k], sr));
    float ni = fmaf(P.cr4[k], zi[k], fmaf(P.ci4[k], zr[k], si));
    zr[k] = nr;
    zi[k] = ni;
    o0[k] = y0;
    o1[k] = y1;
    o2[k] = y2;
    o3[k] = nr;  // Re(z[t+3])
  }
}

// ---------------- carry ----------------
__global__ __launch_bounds__(256, 2) void carry_kernel(
    const float* __restrict__ x, const float* __restrict__ decay,
    const float* __restrict__ freq, float2* __restrict__ agg) {
  const int c = blockIdx.x, b = blockIdx.y;
  const int d = threadIdx.x * 4;

  RPow P;
  load_rpow(decay, freq, d, P);

  const size_t xoff = ((size_t)b * T_LEN + (size_t)c * L_CHUNK) * D_DIM + d;
  const float4* xq = (const float4*)(x + xoff);

  float zr[4] = {0.f, 0.f, 0.f, 0.f}, zi[4] = {0.f, 0.f, 0.f, 0.f};
  float4 A0, A1, A2, A3, B0, B1, B2, B3;
  LOADG(xq, 0, A0, A1, A2, A3);
  LOADG(xq, 1, B0, B1, B2, B3);
#pragma unroll
  for (int g = 0; g < G_GROUPS; g += 2) {
    step_carry(P, A0, A1, A2, A3, zr, zi);
    if (g + 2 < G_GROUPS) LOADG(xq, g + 2, A0, A1, A2, A3);
    step_carry(P, B0, B1, B2, B3, zr, zi);
    if (g + 3 < G_GROUPS) LOADG(xq, g + 3, B0, B1, B2, B3);
  }

  // plain coalesced stores; kernel-boundary coherence covers visibility
  float4* ap = (float4*)(agg + ((size_t)(b * C_CHUNKS + c)) * D_DIM + d);
  ap[0] = make_float4(zr[0], zi[0], zr[1], zi[1]);
  ap[1] = make_float4(zr[2], zi[2], zr[3], zi[3]);
}

// ---------------- scan (Kogge-Stone over chunk carries) ----------------
__global__ __launch_bounds__(256) void scan_kernel(
    const float* __restrict__ decay, const float* __restrict__ freq,
    float2* __restrict__ agg) {
  const int slab = blockIdx.x, b = blockIdx.y;
  const int tid = threadIdx.x;
  __shared__ float2 A[8][C_CHUNKS + 2];
  const int dbase = slab * 8;

  {
    int dd = tid & 7;
    for (int j = tid >> 3; j < C_CHUNKS; j += 32)
      A[dd][j] = agg[((size_t)(b * C_CHUNKS + j)) * D_DIM + dbase + dd];
  }

  // M = r^L per slab channel; squared each step -> r^(L*2^k) (no large-arg trig)
  float Mr[8], Mi[8];
#pragma unroll
  for (int q = 0; q < 8; ++q) {
    float aq = fabsf(decay[dbase + q]);
    float wq = freq[dbase + q];
    float e = expf(-aq * (float)L_CHUNK);
    Mr[q] = e * cosf(wq * (float)L_CHUNK);
    Mi[q] = e * sinf(wq * (float)L_CHUNK);
  }
  __syncthreads();

  const int cc = tid;
  const bool own = (cc < C_CHUNKS);
  float Ir[8], Ii[8];
  if (own) {
#pragma unroll
    for (int q = 0; q < 8; ++q) {
      float2 v = A[q][cc];
      Ir[q] = v.x;
      Ii[q] = v.y;
    }
  }

#pragma unroll
  for (int k = 0; k < 7; ++k) {  // 2^7 == C_CHUNKS
    const int off = 1 << k;
    if (own && cc >= off) {
#pragma unroll
      for (int q = 0; q < 8; ++q) {
        float2 p = A[q][cc - off];
        Ir[q] = fmaf(Mr[q], p.x, fmaf(-Mi[q], p.y, Ir[q]));
        Ii[q] = fmaf(Mr[q], p.y, fmaf(Mi[q], p.x, Ii[q]));
      }
    }
    __syncthreads();
    if (own) {
#pragma unroll
      for (int q = 0; q < 8; ++q) A[q][cc] = make_float2(Ir[q], Ii[q]);
    }
    __syncthreads();
#pragma unroll
    for (int q = 0; q < 8; ++q) {
      float nr = fmaf(Mr[q], Mr[q], -Mi[q] * Mi[q]);
      Mi[q] = 2.f * Mr[q] * Mi[q];
      Mr[q] = nr;
    }
  }

  // writeback EXCLUSIVE prefix: prefix[j] = inclusive[j-1], prefix[0] = 0
  {
    int dd = tid & 7;
    for (int j = tid >> 3; j < C_CHUNKS; j += 32) {
      float2 v = (j == 0) ? make_float2(0.f, 0.f) : A[dd][j - 1];
      agg[((size_t)(b * C_CHUNKS + j)) * D_DIM + dbase + dd] = v;
    }
  }
}

// ---------------- final ----------------
__global__ __launch_bounds__(256, 2) void final_kernel(
    const float* __restrict__ x, const float* __restrict__ decay,
    const float* __restrict__ freq, const float2* __restrict__ agg,
    float* __restrict__ y) {
  const int c = blockIdx.x, b = blockIdx.y;
  const int d = threadIdx.x * 4;

  RPow P;
  load_rpow(decay, freq, d, P);

  const size_t xoff = ((size_t)b * T_LEN + (size_t)c * L_CHUNK) * D_DIM + d;
  const float4* xq = (const float4*)(x + xoff);
  floatx4* yp = (floatx4*)(y + xoff);

  const float4* ap =
      (const float4*)(agg + ((size_t)(b * C_CHUNKS + c)) * D_DIM + d);
  float4 q0 = ap[0], q1 = ap[1];
  float zr[4] = {q0.x, q0.z, q1.x, q1.z};
  float zi[4] = {q0.y, q0.w, q1.y, q1.w};

  float4 A0, A1, A2, A3, B0, B1, B2, B3;
  LOADG(xq, 0, A0, A1, A2, A3);
  LOADG(xq, 1, B0, B1, B2, B3);
#pragma unroll
  for (int g = 0; g < G_GROUPS; g += 2) {
    floatx4 o0, o1, o2, o3;
    step_out(P, A0, A1, A2, A3, zr, zi, o0, o1, o2, o3);
    if (g + 2 < G_GROUPS) LOADG(xq, g + 2, A0, A1, A2, A3);
    STOREG(yp, g, o0, o1, o2, o3);
    floatx4 p0, p1, p2, p3;
    step_out(P, B0, B1, B2, B3, zr, zi, p0, p1, p2, p3);
    if (g + 3 < G_GROUPS) LOADG(xq, g + 3, B0, B1, B2, B3);
    STOREG(yp, g + 1, p0, p1, p2, p3);
  }
}

extern "C" void kernel_launch(void* const* d_in, const int* in_sizes, int n_in,
                              void* d_out, int out_size, void* d_ws, size_t ws_size,
                              hipStream_t stream) {
  const float* x     = (const float*)d_in[0];
  const float* decay = (const float*)d_in[1];
  const float* freq  = (const float*)d_in[2];
  float* y = (float*)d_out;

  float2* agg = (float2*)d_ws;  // B*C*D*8 B = 4 MiB

  dim3 block(256);
  // chunk C-1's raw carry is never consumed (scan writes its prefix over it,
  // and its inclusive value is discarded) -> skip that block.
  carry_kernel<<<dim3(C_CHUNKS - 1, B_BATCH), block, 0, stream>>>(x, decay,
                                                                  freq, agg);
  scan_kernel<<<dim3(D_DIM / 8, B_BATCH), block, 0, stream>>>(decay, freq, agg);
  final_kernel<<<dim3(C_CHUNKS, B_BATCH), block, 0, stream>>>(x, decay, freq,
                                                              agg, y);
}